// Round 8
// baseline (253.531 us; speedup 1.0000x reference)
//
#include <hip/hip_runtime.h>
#include <hip/hip_bf16.h>
#include <math.h>

#define S_LEN 2048
#define B_SZ  4
#define E_DIM 512
#define H_NUM 8
#define HD    64
#define FF_DIM 2048
#define NROWS 8192
#define WIN   128

typedef unsigned short u16;
typedef __bf16 bf16x8 __attribute__((ext_vector_type(8)));
typedef float  f32x4  __attribute__((ext_vector_type(4)));

// fp32 -> bf16 round-to-nearest-even
__device__ __forceinline__ u16 f2bf(float f) {
  union { float f; unsigned u; } v; v.f = f;
  unsigned u = v.u;
  return (u16)((u + 0x7fffu + ((u >> 16) & 1u)) >> 16);
}

// async global->LDS, 16B per lane; LDS dest = wave-uniform base + lane*16
__device__ __forceinline__ void gl_lds16(const u16* gp, u16* lp) {
  __builtin_amdgcn_global_load_lds(
      (const __attribute__((address_space(1))) unsigned int*)gp,
      (__attribute__((address_space(3))) unsigned int*)lp, 16, 0, 0);
}

// ---------------------------------------------------------------------------
// prep: fused weight-cast (blocks 0..3071) + x+pos (blocks 3072..7167)
// ---------------------------------------------------------------------------
__global__ __launch_bounds__(256) void prep_kernel(
    const float* __restrict__ s0, const float* __restrict__ s1,
    const float* __restrict__ s2, const float* __restrict__ s3,
    u16* __restrict__ d0, u16* __restrict__ d1,
    u16* __restrict__ d2, u16* __restrict__ d3,
    const float* __restrict__ x, const float* __restrict__ pos,
    float* __restrict__ xp, u16* __restrict__ xpb) {
  int bx = blockIdx.x;
  if (bx < 3072) {
    const int n0 = 196608, n1 = 65536, n2 = 262144;
    int i = bx * blockDim.x + threadIdx.x;
    const float4* sp; ushort4* dp; int off;
    if (i < n0)                { sp = (const float4*)s0; dp = (ushort4*)d0; off = i; }
    else if (i < n0 + n1)      { sp = (const float4*)s1; dp = (ushort4*)d1; off = i - n0; }
    else if (i < n0 + n1 + n2) { sp = (const float4*)s2; dp = (ushort4*)d2; off = i - n0 - n1; }
    else                       { sp = (const float4*)s3; dp = (ushort4*)d3; off = i - n0 - n1 - n2; }
    float4 v = sp[off];
    ushort4 o; o.x = f2bf(v.x); o.y = f2bf(v.y); o.z = f2bf(v.z); o.w = f2bf(v.w);
    dp[off] = o;
  } else {
    int idx = (bx - 3072) * blockDim.x + threadIdx.x;
    float4 xv = ((const float4*)x)[idx];
    float4 pv = ((const float4*)pos)[idx & 511];
    float4 o;
    o.x = xv.x + pv.x; o.y = xv.y + pv.y; o.z = xv.z + pv.z; o.w = xv.w + pv.w;
    ((float4*)xp)[idx] = o;
    ushort4 ob; ob.x = f2bf(o.x); ob.y = f2bf(o.y); ob.z = f2bf(o.z); ob.w = f2bf(o.w);
    ((ushort4*)xpb)[idx] = ob;
  }
}

// ---------------------------------------------------------------------------
// bf16 MFMA GEMM (unchanged from R7): 128xBN tile, BK=64, 4 waves, swizzled
// LDS, double-buffered global_load_lds, XCD remap, coalesced LDS epilogue.
// ---------------------------------------------------------------------------
#define GBK 64

template <int BN, int GY>
__global__ __launch_bounds__(256) void mfma_gemm(
    const u16* __restrict__ A, const u16* __restrict__ W,
    const float* __restrict__ bias, float* __restrict__ outf,
    u16* __restrict__ outb, int M, int N, int K, int mode,
    u16* __restrict__ qb, u16* __restrict__ kb, u16* __restrict__ vb) {
  constexpr int TJ = BN / 32;
  __shared__ u16 SMEM[2 * 128 * GBK + 2 * BN * GBK];
  u16* As0 = SMEM;
  u16* Bs0 = SMEM + 2 * 128 * GBK;
  int tid = threadIdx.x;
  int lane = tid & 63;
  int w = tid >> 6;
  int lin = blockIdx.y * 64 + blockIdx.x;
  int xcd = lin & 7, slot = lin >> 3;
  int jj = slot % GY;
  int mm = (slot / GY) * 8 + xcd;
  int m0 = mm * 128;
  int j0 = jj * BN;
  int wrow = (w >> 1) * 64;
  int wcol = (w & 1) * (BN / 2);
  int lm = lane & 15;
  int kq = lane >> 4;
  int sw = lm & 7;
  int r8 = lane >> 3;
  int csrc = ((lane & 7) ^ r8) << 3;

  f32x4 acc[4][TJ];
#pragma unroll
  for (int i = 0; i < 4; i++)
#pragma unroll
    for (int j = 0; j < TJ; j++) acc[i][j] = (f32x4){0.f, 0.f, 0.f, 0.f};

  const u16* Ab = A + (size_t)m0 * K;
  const u16* Wb = W + (size_t)j0 * K;

  size_t soff[4];
#pragma unroll
  for (int u = 0; u < 4; u++)
    soff[u] = (size_t)(u * 32 + w * 8 + r8) * K + csrc;

  auto stage = [&](int kt, int pb) {
#pragma unroll
    for (int u = 0; u < 4; u++)
      gl_lds16(&Ab[soff[u] + kt], &As0[pb * 128 * GBK + (u * 4 + w) * 512]);
#pragma unroll
    for (int u = 0; u < TJ; u++)
      gl_lds16(&Wb[soff[u] + kt], &Bs0[pb * BN * GBK + (u * 4 + w) * 512]);
  };

  stage(0, 0);
  int pb = 0;
  for (int kt = 0; kt < K; kt += GBK) {
    __syncthreads();
    if (kt + GBK < K) stage(kt + GBK, pb ^ 1);
#pragma unroll
    for (int k2 = 0; k2 < GBK; k2 += 32) {
      int cc = ((((k2 >> 3) + kq) ^ sw) << 3);
      bf16x8 af[4], bfr[TJ];
#pragma unroll
      for (int t = 0; t < 4; t++)
        af[t] = *(const bf16x8*)&As0[pb * 128 * GBK + (wrow + t * 16 + lm) * GBK + cc];
#pragma unroll
      for (int tj = 0; tj < TJ; tj++)
        bfr[tj] = *(const bf16x8*)&Bs0[pb * BN * GBK + (wcol + tj * 16 + lm) * GBK + cc];
#pragma unroll
      for (int ti = 0; ti < 4; ti++)
#pragma unroll
        for (int tj = 0; tj < TJ; tj++)
          acc[ti][tj] = __builtin_amdgcn_mfma_f32_16x16x32_bf16(
              af[ti], bfr[tj], acc[ti][tj], 0, 0, 0);
    }
    pb ^= 1;
  }

  __syncthreads();
  if (mode == 0) {
    float* Cf = (float*)SMEM;
    constexpr int CF = BN + 4;
#pragma unroll
    for (int p = 0; p < 2; p++) {
      if ((w >> 1) == p) {
#pragma unroll
        for (int tj = 0; tj < TJ; tj++) {
          float bv = bias[j0 + wcol + tj * 16 + lm];
#pragma unroll
          for (int ti = 0; ti < 4; ti++)
#pragma unroll
            for (int r = 0; r < 4; r++)
              Cf[(ti * 16 + kq * 4 + r) * CF + wcol + tj * 16 + lm] =
                  acc[ti][tj][r] + bv;
        }
      }
      __syncthreads();
      constexpr int RC4 = BN / 4;
#pragma unroll
      for (int it = 0; it < 64 * RC4 / 256; it++) {
        int id = it * 256 + tid;
        int row = id / RC4, c4 = (id % RC4) * 4;
        float4 vq = *(float4*)&Cf[row * CF + c4];
        *(float4*)&outf[(size_t)(m0 + p * 64 + row) * N + j0 + c4] = vq;
      }
      __syncthreads();
    }
  } else {
    u16* Cs = (u16*)SMEM;
    constexpr int CS = BN + 8;
    int which = j0 >> 9;
    float qsc = (mode == 2 && which == 0) ? 0.125f : 1.f;
#pragma unroll
    for (int tj = 0; tj < TJ; tj++) {
      float bv = bias[j0 + wcol + tj * 16 + lm];
#pragma unroll
      for (int ti = 0; ti < 4; ti++)
#pragma unroll
        for (int r = 0; r < 4; r++) {
          float val = acc[ti][tj][r] + bv;
          if (mode == 1) val = fmaxf(val, 0.f);
          Cs[(wrow + ti * 16 + kq * 4 + r) * CS + wcol + tj * 16 + lm] =
              f2bf(val * qsc);
        }
    }
    __syncthreads();
    constexpr int RC8 = BN / 8;
#pragma unroll
    for (int it = 0; it < 128 * RC8 / 256; it++) {
      int id = it * 256 + tid;
      int row = id / RC8, c8 = (id % RC8) * 8;
      uint4 vq = *(uint4*)&Cs[row * CS + c8];
      if (mode == 1) {
        *(uint4*)&outb[(size_t)(m0 + row) * N + j0 + c8] = vq;
      } else {
        int e = (j0 & 511) + c8;
        int h = e >> 6, d0 = e & 63;
        int m = m0 + row, s = m >> 2, b = m & 3;
        u16* dst = (which == 0) ? qb : (which == 1) ? kb : vb;
        *(uint4*)&dst[((size_t)(b * H_NUM + h) * S_LEN + s) * HD + d0] = vq;
      }
    }
  }
}

// ---------------------------------------------------------------------------
// MFMA attention: block = 64 queries x (b,h); XCD remap.
// Swizzle keys: Qs/Ks (global_load_lds) use row&7; Vs/Ps/epilogue use
// (row&7)^((row>>2)&7) -- conflict-free for both scatter writes and b128 reads.
// Globals chunk trimmed: QK tj=0 only, PV k2<32 (ng<=8 valid cols).
// LDS = 32KB exactly -> up to 5 blocks/CU.
// ---------------------------------------------------------------------------
__global__ __launch_bounds__(256) void attn_mfma_kernel(
    const u16* __restrict__ q, const u16* __restrict__ k,
    const u16* __restrict__ v, u16* __restrict__ yb) {
  __shared__ u16 Qs[64 * 64];   // [q][d] key row&7; reused for O epilogue
  __shared__ u16 Ks[64 * 64];   // [c][d] key row&7
  __shared__ u16 Vs[64 * 64];   // [d][c] key (d&7)^((d>>2)&7)
  __shared__ u16 Ps[64 * 64];   // [q][c] key (q&7)^((q>>2)&7)
  int tid = threadIdx.x, lane = tid & 63, w = tid >> 6;
  int quad = lane >> 4, lm = lane & 15;
  int sw = lm & 7;
  int r8 = lane >> 3;
  int csrc = ((lane & 7) ^ r8) << 3;
  int lin = blockIdx.y * 32 + blockIdx.x;
  int xcd = lin & 7, slot = lin >> 3;
  int bh = xcd * 4 + (slot >> 5);
  int i0 = (slot & 31) * 64;
  int b = bh >> 3, h = bh & 7;
  const u16* qp = q + ((size_t)bh * S_LEN + i0) * HD;
  const u16* kp = k + (size_t)bh * S_LEN * HD;
  const u16* vp = v + (size_t)bh * S_LEN * HD;

#pragma unroll
  for (int u = 0; u < 2; u++) {
    int seg = u * 4 + w;
    int r = seg * 8 + r8;
    gl_lds16(&qp[(size_t)r * HD + csrc], &Qs[seg * 512]);
  }

  int cl = i0 - WIN; if (cl < 0) cl = 0;
  int chi = i0 + 63 + WIN; if (chi > S_LEN - 1) chi = S_LEN - 1;
  int nch = (chi - cl + 64) >> 6;
  int tlo = (cl + 255) >> 8;
  int thi0 = (chi >> 8) + 1;
  int ng = tlo + 8 - thi0;

  float m_i[4], l_i[4];
  f32x4 o[4];
#pragma unroll
  for (int r = 0; r < 4; r++) { m_i[r] = -INFINITY; l_i[r] = 0.f; }
#pragma unroll
  for (int tj = 0; tj < 4; tj++) o[tj] = (f32x4){0.f, 0.f, 0.f, 0.f};

  // per-lane read keys (row-dependent, hoisted)
  int arow = w * 16 + lm;                              // P A-frag row (q)
  int kpr = (arow & 7) ^ ((arow >> 2) & 7);

  for (int ch = 0; ch <= nch; ch++) {
    bool is_g = (ch == nch);
    int c0 = cl + (ch << 6);
    __syncthreads();
    if (!is_g) {
#pragma unroll
      for (int u = 0; u < 2; u++) {
        int seg = u * 4 + w;
        int r = seg * 8 + r8;
        gl_lds16(&kp[(size_t)(c0 + r) * HD + csrc], &Ks[seg * 512]);
      }
      // V transpose: coalesced 8B row loads -> conflict-free swizzled stores
#pragma unroll
      for (int it = 0; it < 4; it++) {
        int flat = it * 256 + tid;
        int c = flat >> 4;
        int d0 = (flat & 15) << 2;
        ushort4 vv = make_ushort4(0, 0, 0, 0);
        int src = c0 + c;
        if (src <= chi) vv = *(const ushort4*)&vp[(size_t)src * HD + d0];
        u16 arr[4] = {vv.x, vv.y, vv.z, vv.w};
#pragma unroll
        for (int jd = 0; jd < 4; jd++) {
          int d = d0 + jd;
          int kd = (d & 7) ^ ((d >> 2) & 7);
          Vs[d * 64 + ((((c >> 3) ^ kd) << 3) | (c & 7))] = arr[jd];
        }
      }
    } else {
      if (w == 0) {
        int rr = lane >> 3;
        int grow = (rr < tlo) ? (rr << 8) : ((thi0 + rr - tlo) << 8);
        if (rr >= ng) grow = 0;
        gl_lds16(&kp[(size_t)grow * HD + (((lane & 7) ^ rr) << 3)], &Ks[0]);
      }
      for (int e = tid; e < 64 * 8; e += 256) {
        int d = e & 63, cg = e >> 6;
        if (cg < ng) {
          int gs = (cg < tlo) ? (cg << 8) : ((thi0 + cg - tlo) << 8);
          int kd = (d & 7) ^ ((d >> 2) & 7);
          Vs[d * 64 + (kd << 3) + cg] = vp[(size_t)gs * HD + d];
        }
      }
    }
    __syncthreads();

    // QK^T (globals chunk: tj=0 only; cols 16..63 are all invalid anyway)
    f32x4 s[4];
#pragma unroll
    for (int tj = 0; tj < 4; tj++) s[tj] = (f32x4){0.f, 0.f, 0.f, 0.f};
    int tjn = is_g ? 1 : 4;
#pragma unroll
    for (int k2 = 0; k2 < 64; k2 += 32) {
      int cb = (k2 >> 3) + quad;
      bf16x8 a = *(const bf16x8*)&Qs[(w * 16 + lm) * 64 + ((cb ^ sw) << 3)];
      for (int tj = 0; tj < tjn; tj++) {
        bf16x8 bfr = *(const bf16x8*)&Ks[(tj * 16 + lm) * 64 + ((cb ^ sw) << 3)];
        s[tj] = __builtin_amdgcn_mfma_f32_16x16x32_bf16(a, bfr, s[tj], 0, 0, 0);
      }
    }
#pragma unroll
    for (int tj = 0; tj < 4; tj++) {
      int cidx = tj * 16 + lm;
      bool inval = is_g ? (cidx >= ng) : (c0 + cidx > chi);
      if (inval) {
        s[tj][0] = -INFINITY; s[tj][1] = -INFINITY;
        s[tj][2] = -INFINITY; s[tj][3] = -INFINITY;
      }
    }
    // online softmax
#pragma unroll
    for (int r = 0; r < 4; r++) {
      float mx = fmaxf(fmaxf(s[0][r], s[1][r]), fmaxf(s[2][r], s[3][r]));
      mx = fmaxf(mx, __shfl_xor(mx, 1)); mx = fmaxf(mx, __shfl_xor(mx, 2));
      mx = fmaxf(mx, __shfl_xor(mx, 4)); mx = fmaxf(mx, __shfl_xor(mx, 8));
      float mnew = fmaxf(m_i[r], mx);
      float al = __expf(m_i[r] - mnew);
      float rs = 0.f;
#pragma unroll
      for (int tj = 0; tj < 4; tj++) {
        float p = __expf(s[tj][r] - mnew);
        s[tj][r] = p; rs += p;
      }
      rs += __shfl_xor(rs, 1); rs += __shfl_xor(rs, 2);
      rs += __shfl_xor(rs, 4); rs += __shfl_xor(rs, 8);
      l_i[r] = l_i[r] * al + rs;
      m_i[r] = mnew;
      o[0][r] *= al; o[1][r] *= al; o[2][r] *= al; o[3][r] *= al;
    }
    // P -> LDS (swizzled, conflict-free; same-wave write->read)
#pragma unroll
    for (int tj = 0; tj < 4; tj++) {
      int cch = tj * 2 + (lm >> 3);
      int cof = lm & 7;
#pragma unroll
      for (int r = 0; r < 4; r++) {
        int row = w * 16 + quad * 4 + r;
        int kp2 = (row & 7) ^ ((row >> 2) & 7);
        Ps[row * 64 + ((cch ^ kp2) << 3) + cof] = f2bf(s[tj][r]);
      }
    }
    // PV (globals chunk: only c<32 needed since ng<=8; P is 0 beyond ng)
    int kend = is_g ? 32 : 64;
#pragma unroll
    for (int k2 = 0; k2 < 64; k2 += 32) {
      if (k2 >= kend) break;
      int cb = (k2 >> 3) + quad;
      bf16x8 a = *(const bf16x8*)&Ps[arow * 64 + ((cb ^ kpr) << 3)];
#pragma unroll
      for (int tj = 0; tj < 4; tj++) {
        int vrow = tj * 16 + lm;
        int kv = (vrow & 7) ^ ((vrow >> 2) & 7);
        bf16x8 bfr = *(const bf16x8*)&Vs[vrow * 64 + ((cb ^ kv) << 3)];
        o[tj] = __builtin_amdgcn_mfma_f32_16x16x32_bf16(a, bfr, o[tj], 0, 0, 0);
      }
    }
  }

  // coalesced epilogue: O -> Qs (dead, swizzled) -> 16B row stores
  __syncthreads();
#pragma unroll
  for (int r = 0; r < 4; r++) {
    float inv = 1.f / l_i[r];
    int row = w * 16 + quad * 4 + r;
    int kq2 = (row & 7) ^ ((row >> 2) & 7);
#pragma unroll
    for (int tj = 0; tj < 4; tj++) {
      int cch = tj * 2 + (lm >> 3);
      Qs[row * 64 + ((cch ^ kq2) << 3) + (lm & 7)] = f2bf(o[tj][r] * inv);
    }
  }
  __syncthreads();
#pragma unroll
  for (int it = 0; it < 2; it++) {
    int id = it * 256 + tid;
    int row = id >> 3, cch = id & 7;
    int kq2 = (row & 7) ^ ((row >> 2) & 7);
    uint4 vq = *(uint4*)&Qs[row * 64 + ((cch ^ kq2) << 3)];
    *(uint4*)&yb[((size_t)(i0 + row) * B_SZ + b) * E_DIM + h * HD + cch * 8] = vq;
  }
}

// ---------------------------------------------------------------------------
// residual add + LayerNorm; optional bf16 secondary output
// ---------------------------------------------------------------------------
__global__ __launch_bounds__(256) void add_ln_kernel(
    const float* __restrict__ a, const float* __restrict__ r,
    const float* __restrict__ g, const float* __restrict__ be,
    float* __restrict__ out, u16* __restrict__ outb) {
  int wave = threadIdx.x >> 6;
  int lane = threadIdx.x & 63;
  int row = blockIdx.x * 4 + wave;
  const float* ar = a + (size_t)row * E_DIM;
  const float* rr = r + (size_t)row * E_DIM;
  float vals[8];
  float s = 0.f;
#pragma unroll
  for (int t = 0; t < 8; t++) {
    vals[t] = ar[t * 64 + lane] + rr[t * 64 + lane];
    s += vals[t];
  }
#pragma unroll
  for (int o = 32; o >= 1; o >>= 1) s += __shfl_xor(s, o, 64);
  float mu = s * (1.f / E_DIM);
  float vs = 0.f;
#pragma unroll
  for (int t = 0; t < 8; t++) { float d = vals[t] - mu; vs += d * d; }
#pragma unroll
  for (int o = 32; o >= 1; o >>= 1) vs += __shfl_xor(vs, o, 64);
  float inv = rsqrtf(vs * (1.f / E_DIM) + 1e-5f);
  float* orow = out + (size_t)row * E_DIM;
  u16* obrow = outb ? outb + (size_t)row * E_DIM : nullptr;
#pragma unroll
  for (int t = 0; t < 8; t++) {
    int e = t * 64 + lane;
    float val = (vals[t] - mu) * inv * g[e] + be[e];
    orow[e] = val;
    if (obrow) obrow[e] = f2bf(val);
  }
}

// ---------------------------------------------------------------------------
// launch
// ---------------------------------------------------------------------------
extern "C" void kernel_launch(void* const* d_in, const int* in_sizes, int n_in,
                              void* d_out, int out_size, void* d_ws, size_t ws_size,
                              hipStream_t stream) {
  const float* x     = (const float*)d_in[0];
  const float* pos   = (const float*)d_in[1];
  const float* in_w  = (const float*)d_in[2];
  const float* in_b  = (const float*)d_in[3];
  const float* out_w = (const float*)d_in[4];
  const float* out_b = (const float*)d_in[5];
  const float* w1    = (const float*)d_in[6];
  const float* b1    = (const float*)d_in[7];
  const float* w2    = (const float*)d_in[8];
  const float* b2    = (const float*)d_in[9];
  const float* g1    = (const float*)d_in[10];
  const float* be1   = (const float*)d_in[11];
  const float* g2    = (const float*)d_in[12];
  const float* be2   = (const float*)d_in[13];
  float* out = (float*)d_out;

  char* base = (char*)d_ws;
  float* xp    = (float*)(base);
  u16*   xpb   = (u16*)(base + ((size_t)16 << 20));
  u16*   qb    = (u16*)(base + ((size_t)24 << 20));
  u16*   kb    = (u16*)(base + ((size_t)32 << 20));
  u16*   vb    = (u16*)(base + ((size_t)40 << 20));
  u16*   ybf   = (u16*)(base + ((size_t)48 << 20));
  float* aprj  = (float*)(base + ((size_t)56 << 20));
  u16*   inwb  = (u16*)(base + ((size_t)72 << 20));
  u16*   outwb = (u16*)(base + ((size_t)74 << 20));
  u16*   w1b   = (u16*)(base + ((size_t)76 << 20));
  u16*   w2b   = (u16*)(base + ((size_t)78 << 20));
  float* x1    = xp;
  u16*   x1b   = xpb;
  u16*   ff1b  = qb;      // 24M..56M
  float* ff2   = aprj;

  prep_kernel<<<7168, 256, 0, stream>>>(in_w, out_w, w1, w2, inwb, outwb, w1b, w2b,
                                        x, pos, xp, xpb);
  mfma_gemm<128, 12><<<dim3(64, 12), 256, 0, stream>>>(xpb, inwb, in_b, nullptr, nullptr,
                                                       NROWS, 1536, 512, 2, qb, kb, vb);
  attn_mfma_kernel<<<dim3(32, 32), 256, 0, stream>>>(qb, kb, vb, ybf);
  mfma_gemm<64, 8><<<dim3(64, 8), 256, 0, stream>>>(ybf, outwb, out_b, aprj, nullptr,
                                                    NROWS, 512, 512, 0, nullptr, nullptr, nullptr);
  add_ln_kernel<<<2048, 256, 0, stream>>>(xp, aprj, g1, be1, x1, x1b);
  mfma_gemm<128, 16><<<dim3(64, 16), 256, 0, stream>>>(x1b, w1b, b1, nullptr, ff1b,
                                                       NROWS, 2048, 512, 1, nullptr, nullptr, nullptr);
  mfma_gemm<64, 8><<<dim3(64, 8), 256, 0, stream>>>(ff1b, w2b, b2, ff2, nullptr,
                                                    NROWS, 512, 2048, 0, nullptr, nullptr, nullptr);
  add_ln_kernel<<<2048, 256, 0, stream>>>(x1, ff2, g2, be2, out, nullptr);
}

// Round 9
// 251.039 us; speedup vs baseline: 1.0099x; 1.0099x over previous
//
#include <hip/hip_runtime.h>
#include <hip/hip_bf16.h>
#include <math.h>

#define S_LEN 2048
#define B_SZ  4
#define E_DIM 512
#define H_NUM 8
#define HD    64
#define FF_DIM 2048
#define NROWS 8192
#define WIN   128

typedef unsigned short u16;
typedef __bf16 bf16x8 __attribute__((ext_vector_type(8)));
typedef float  f32x4  __attribute__((ext_vector_type(4)));

// fp32 -> bf16 round-to-nearest-even
__device__ __forceinline__ u16 f2bf(float f) {
  union { float f; unsigned u; } v; v.f = f;
  unsigned u = v.u;
  return (u16)((u + 0x7fffu + ((u >> 16) & 1u)) >> 16);
}

// async global->LDS, 16B per lane; LDS dest = wave-uniform base + lane*16
__device__ __forceinline__ void gl_lds16(const u16* gp, u16* lp) {
  __builtin_amdgcn_global_load_lds(
      (const __attribute__((address_space(1))) unsigned int*)gp,
      (__attribute__((address_space(3))) unsigned int*)lp, 16, 0, 0);
}

// ---------------------------------------------------------------------------
// prep: fused weight-cast (blocks 0..3071) + x+pos (blocks 3072..7167)
// ---------------------------------------------------------------------------
__global__ __launch_bounds__(256) void prep_kernel(
    const float* __restrict__ s0, const float* __restrict__ s1,
    const float* __restrict__ s2, const float* __restrict__ s3,
    u16* __restrict__ d0, u16* __restrict__ d1,
    u16* __restrict__ d2, u16* __restrict__ d3,
    const float* __restrict__ x, const float* __restrict__ pos,
    float* __restrict__ xp, u16* __restrict__ xpb) {
  int bx = blockIdx.x;
  if (bx < 3072) {
    const int n0 = 196608, n1 = 65536, n2 = 262144;
    int i = bx * blockDim.x + threadIdx.x;
    const float4* sp; ushort4* dp; int off;
    if (i < n0)                { sp = (const float4*)s0; dp = (ushort4*)d0; off = i; }
    else if (i < n0 + n1)      { sp = (const float4*)s1; dp = (ushort4*)d1; off = i - n0; }
    else if (i < n0 + n1 + n2) { sp = (const float4*)s2; dp = (ushort4*)d2; off = i - n0 - n1; }
    else                       { sp = (const float4*)s3; dp = (ushort4*)d3; off = i - n0 - n1 - n2; }
    float4 v = sp[off];
    ushort4 o; o.x = f2bf(v.x); o.y = f2bf(v.y); o.z = f2bf(v.z); o.w = f2bf(v.w);
    dp[off] = o;
  } else {
    int idx = (bx - 3072) * blockDim.x + threadIdx.x;
    float4 xv = ((const float4*)x)[idx];
    float4 pv = ((const float4*)pos)[idx & 511];
    float4 o;
    o.x = xv.x + pv.x; o.y = xv.y + pv.y; o.z = xv.z + pv.z; o.w = xv.w + pv.w;
    ((float4*)xp)[idx] = o;
    ushort4 ob; ob.x = f2bf(o.x); ob.y = f2bf(o.y); ob.z = f2bf(o.z); ob.w = f2bf(o.w);
    ((ushort4*)xpb)[idx] = ob;
  }
}

// ---------------------------------------------------------------------------
// bf16 MFMA GEMM (unchanged from R7): 128xBN tile, BK=64, 4 waves, swizzled
// LDS, double-buffered global_load_lds, XCD remap, coalesced LDS epilogue.
// ---------------------------------------------------------------------------
#define GBK 64

template <int BN, int GY>
__global__ __launch_bounds__(256) void mfma_gemm(
    const u16* __restrict__ A, const u16* __restrict__ W,
    const float* __restrict__ bias, float* __restrict__ outf,
    u16* __restrict__ outb, int M, int N, int K, int mode,
    u16* __restrict__ qb, u16* __restrict__ kb, u16* __restrict__ vb) {
  constexpr int TJ = BN / 32;
  __shared__ u16 SMEM[2 * 128 * GBK + 2 * BN * GBK];
  u16* As0 = SMEM;
  u16* Bs0 = SMEM + 2 * 128 * GBK;
  int tid = threadIdx.x;
  int lane = tid & 63;
  int w = tid >> 6;
  int lin = blockIdx.y * 64 + blockIdx.x;
  int xcd = lin & 7, slot = lin >> 3;
  int jj = slot % GY;
  int mm = (slot / GY) * 8 + xcd;
  int m0 = mm * 128;
  int j0 = jj * BN;
  int wrow = (w >> 1) * 64;
  int wcol = (w & 1) * (BN / 2);
  int lm = lane & 15;
  int kq = lane >> 4;
  int sw = lm & 7;
  int r8 = lane >> 3;
  int csrc = ((lane & 7) ^ r8) << 3;

  f32x4 acc[4][TJ];
#pragma unroll
  for (int i = 0; i < 4; i++)
#pragma unroll
    for (int j = 0; j < TJ; j++) acc[i][j] = (f32x4){0.f, 0.f, 0.f, 0.f};

  const u16* Ab = A + (size_t)m0 * K;
  const u16* Wb = W + (size_t)j0 * K;

  size_t soff[4];
#pragma unroll
  for (int u = 0; u < 4; u++)
    soff[u] = (size_t)(u * 32 + w * 8 + r8) * K + csrc;

  auto stage = [&](int kt, int pb) {
#pragma unroll
    for (int u = 0; u < 4; u++)
      gl_lds16(&Ab[soff[u] + kt], &As0[pb * 128 * GBK + (u * 4 + w) * 512]);
#pragma unroll
    for (int u = 0; u < TJ; u++)
      gl_lds16(&Wb[soff[u] + kt], &Bs0[pb * BN * GBK + (u * 4 + w) * 512]);
  };

  stage(0, 0);
  int pb = 0;
  for (int kt = 0; kt < K; kt += GBK) {
    __syncthreads();
    if (kt + GBK < K) stage(kt + GBK, pb ^ 1);
#pragma unroll
    for (int k2 = 0; k2 < GBK; k2 += 32) {
      int cc = ((((k2 >> 3) + kq) ^ sw) << 3);
      bf16x8 af[4], bfr[TJ];
#pragma unroll
      for (int t = 0; t < 4; t++)
        af[t] = *(const bf16x8*)&As0[pb * 128 * GBK + (wrow + t * 16 + lm) * GBK + cc];
#pragma unroll
      for (int tj = 0; tj < TJ; tj++)
        bfr[tj] = *(const bf16x8*)&Bs0[pb * BN * GBK + (wcol + tj * 16 + lm) * GBK + cc];
#pragma unroll
      for (int ti = 0; ti < 4; ti++)
#pragma unroll
        for (int tj = 0; tj < TJ; tj++)
          acc[ti][tj] = __builtin_amdgcn_mfma_f32_16x16x32_bf16(
              af[ti], bfr[tj], acc[ti][tj], 0, 0, 0);
    }
    pb ^= 1;
  }

  __syncthreads();
  if (mode == 0) {
    float* Cf = (float*)SMEM;
    constexpr int CF = BN + 4;
#pragma unroll
    for (int p = 0; p < 2; p++) {
      if ((w >> 1) == p) {
#pragma unroll
        for (int tj = 0; tj < TJ; tj++) {
          float bv = bias[j0 + wcol + tj * 16 + lm];
#pragma unroll
          for (int ti = 0; ti < 4; ti++)
#pragma unroll
            for (int r = 0; r < 4; r++)
              Cf[(ti * 16 + kq * 4 + r) * CF + wcol + tj * 16 + lm] =
                  acc[ti][tj][r] + bv;
        }
      }
      __syncthreads();
      constexpr int RC4 = BN / 4;
#pragma unroll
      for (int it = 0; it < 64 * RC4 / 256; it++) {
        int id = it * 256 + tid;
        int row = id / RC4, c4 = (id % RC4) * 4;
        float4 vq = *(float4*)&Cf[row * CF + c4];
        *(float4*)&outf[(size_t)(m0 + p * 64 + row) * N + j0 + c4] = vq;
      }
      __syncthreads();
    }
  } else {
    u16* Cs = (u16*)SMEM;
    constexpr int CS = BN + 8;
    int which = j0 >> 9;
    float qsc = (mode == 2 && which == 0) ? 0.125f : 1.f;
#pragma unroll
    for (int tj = 0; tj < TJ; tj++) {
      float bv = bias[j0 + wcol + tj * 16 + lm];
#pragma unroll
      for (int ti = 0; ti < 4; ti++)
#pragma unroll
        for (int r = 0; r < 4; r++) {
          float val = acc[ti][tj][r] + bv;
          if (mode == 1) val = fmaxf(val, 0.f);
          Cs[(wrow + ti * 16 + kq * 4 + r) * CS + wcol + tj * 16 + lm] =
              f2bf(val * qsc);
        }
    }
    __syncthreads();
    constexpr int RC8 = BN / 8;
#pragma unroll
    for (int it = 0; it < 128 * RC8 / 256; it++) {
      int id = it * 256 + tid;
      int row = id / RC8, c8 = (id % RC8) * 8;
      uint4 vq = *(uint4*)&Cs[row * CS + c8];
      if (mode == 1) {
        *(uint4*)&outb[(size_t)(m0 + row) * N + j0 + c8] = vq;
      } else {
        int e = (j0 & 511) + c8;
        int h = e >> 6, d0 = e & 63;
        int m = m0 + row, s = m >> 2, b = m & 3;
        u16* dst = (which == 0) ? qb : (which == 1) ? kb : vb;
        *(uint4*)&dst[((size_t)(b * H_NUM + h) * S_LEN + s) * HD + d0] = vq;
      }
    }
  }
}

// ---------------------------------------------------------------------------
// V transpose: vb (b,h,s,d) -> vtb (b,h,d,s), LDS 64x64 tile, coalesced both
// sides. 1024 blocks; one-time cost removes per-chunk transpose from attn.
// ---------------------------------------------------------------------------
__global__ __launch_bounds__(256) void vtrans_kernel(
    const u16* __restrict__ vb, u16* __restrict__ vtb) {
  __shared__ u16 Ts[64 * 64];
  int tid = threadIdx.x;
  int lin = blockIdx.x;                  // 32 bh x 32 s-tiles
  int bh = lin >> 5, s0 = (lin & 31) * 64;
  const u16* src = vb + ((size_t)bh * S_LEN + s0) * HD;
#pragma unroll
  for (int it = 0; it < 4; it++) {
    int flat = it * 256 + tid;
    int c = flat >> 4;                   // s-index 0..63
    int d0 = (flat & 15) << 2;
    ushort4 vv = *(const ushort4*)&src[(size_t)c * HD + d0];
    u16 arr[4] = {vv.x, vv.y, vv.z, vv.w};
#pragma unroll
    for (int jd = 0; jd < 4; jd++) {
      int d = d0 + jd;
      int kd = (d & 7) ^ ((d >> 2) & 7);
      Ts[d * 64 + ((((c >> 3) ^ kd) << 3) | (c & 7))] = arr[jd];
    }
  }
  __syncthreads();
  u16* dst = vtb + (size_t)bh * HD * S_LEN + s0;
#pragma unroll
  for (int it = 0; it < 2; it++) {
    int id = it * 256 + tid;
    int row = id >> 3, cch = id & 7;     // row = d
    int kd = (row & 7) ^ ((row >> 2) & 7);
    uint4 vq = *(uint4*)&Ts[row * 64 + ((cch ^ kd) << 3)];
    *(uint4*)&dst[(size_t)row * S_LEN + cch * 8] = vq;
  }
}

// ---------------------------------------------------------------------------
// MFMA attention: block = 64 queries x (b,h); XCD remap. K and V^T staged via
// global_load_lds (row&7 swizzle), DOUBLE-BUFFERED (prefetch chunk ch+1 after
// the barrier, compute ch). No in-loop transpose. LDS 48KB -> 3 blocks/CU.
// ---------------------------------------------------------------------------
__global__ __launch_bounds__(256) void attn_mfma_kernel(
    const u16* __restrict__ q, const u16* __restrict__ k,
    const u16* __restrict__ vt, u16* __restrict__ yb) {
  __shared__ u16 Qs[64 * 64];      // [q][d] key row&7; reused for O epilogue
  __shared__ u16 Ks[2][64 * 64];   // [c][d] key row&7
  __shared__ u16 Vs[2][64 * 64];   // [d][c] key row&7 (from vtb rows)
  __shared__ u16 Ps[64 * 64];      // [q][c] key (q&7)^((q>>2)&7)
  int tid = threadIdx.x, lane = tid & 63, w = tid >> 6;
  int quad = lane >> 4, lm = lane & 15;
  int sw = lm & 7;
  int r8 = lane >> 3;
  int csrc = ((lane & 7) ^ r8) << 3;
  int lin = blockIdx.y * 32 + blockIdx.x;
  int xcd = lin & 7, slot = lin >> 3;
  int bh = xcd * 4 + (slot >> 5);
  int i0 = (slot & 31) * 64;
  int b = bh >> 3, h = bh & 7;
  const u16* qp = q + ((size_t)bh * S_LEN + i0) * HD;
  const u16* kp = k + (size_t)bh * S_LEN * HD;
  const u16* vp = vt + (size_t)bh * HD * S_LEN;   // (d, s) layout

#pragma unroll
  for (int u = 0; u < 2; u++) {
    int seg = u * 4 + w;
    int r = seg * 8 + r8;
    gl_lds16(&qp[(size_t)r * HD + csrc], &Qs[seg * 512]);
  }

  int cl = i0 - WIN; if (cl < 0) cl = 0;
  int chi = i0 + 63 + WIN; if (chi > S_LEN - 1) chi = S_LEN - 1;
  int nch = (chi - cl + 64) >> 6;        // window chunks (wlen mult of 64)
  int tlo = (cl + 255) >> 8;
  int thi0 = (chi >> 8) + 1;
  int ng = tlo + 8 - thi0;

  // stage chunk ch's K and V^T into buffer buf
  auto stageKV = [&](int ch, int buf) {
    if (ch < nch) {
      int c0 = cl + (ch << 6);
#pragma unroll
      for (int u = 0; u < 2; u++) {
        int seg = u * 4 + w;
        int r = seg * 8 + r8;
        gl_lds16(&kp[(size_t)(c0 + r) * HD + csrc], &Ks[buf][seg * 512]);
        gl_lds16(&vp[(size_t)r * S_LEN + c0 + csrc], &Vs[buf][seg * 512]);
      }
    } else {
      if (w == 0) {                      // K globals: 8 rows, one async inst
        int rr = lane >> 3;
        int grow = (rr < tlo) ? (rr << 8) : ((thi0 + rr - tlo) << 8);
        if (rr >= ng) grow = 0;
        gl_lds16(&kp[(size_t)grow * HD + (((lane & 7) ^ rr) << 3)], &Ks[buf][0]);
      }
      // V globals: scalar, chunk 0 -> key d&7
      for (int e = tid; e < 64 * 8; e += 256) {
        int d = e & 63, cg = e >> 6;
        if (cg < ng) {
          int gs = (cg < tlo) ? (cg << 8) : ((thi0 + cg - tlo) << 8);
          Vs[buf][d * 64 + ((d & 7) << 3) + cg] = vp[(size_t)d * S_LEN + gs];
        }
      }
    }
  };

  float m_i[4], l_i[4];
  f32x4 o[4];
#pragma unroll
  for (int r = 0; r < 4; r++) { m_i[r] = -INFINITY; l_i[r] = 0.f; }
#pragma unroll
  for (int tj = 0; tj < 4; tj++) o[tj] = (f32x4){0.f, 0.f, 0.f, 0.f};

  int arow = w * 16 + lm;                // P A-frag row (q)
  int kpr = (arow & 7) ^ ((arow >> 2) & 7);

  stageKV(0, 0);
  for (int ch = 0; ch <= nch; ch++) {
    bool is_g = (ch == nch);
    int c0 = cl + (ch << 6);
    int buf = ch & 1;
    __syncthreads();                     // buf ready; other buf's reads done
    if (ch < nch) stageKV(ch + 1, buf ^ 1);

    // QK^T (globals chunk: tj=0 only; cols 16..63 invalid anyway)
    f32x4 s[4];
#pragma unroll
    for (int tj = 0; tj < 4; tj++) s[tj] = (f32x4){0.f, 0.f, 0.f, 0.f};
    int tjn = is_g ? 1 : 4;
#pragma unroll
    for (int k2 = 0; k2 < 64; k2 += 32) {
      int cb = (k2 >> 3) + quad;
      bf16x8 a = *(const bf16x8*)&Qs[(w * 16 + lm) * 64 + ((cb ^ sw) << 3)];
      for (int tj = 0; tj < tjn; tj++) {
        bf16x8 bfr = *(const bf16x8*)&Ks[buf][(tj * 16 + lm) * 64 + ((cb ^ sw) << 3)];
        s[tj] = __builtin_amdgcn_mfma_f32_16x16x32_bf16(a, bfr, s[tj], 0, 0, 0);
      }
    }
#pragma unroll
    for (int tj = 0; tj < 4; tj++) {
      int cidx = tj * 16 + lm;
      bool inval = is_g ? (cidx >= ng) : (c0 + cidx > chi);
      if (inval) {
        s[tj][0] = -INFINITY; s[tj][1] = -INFINITY;
        s[tj][2] = -INFINITY; s[tj][3] = -INFINITY;
      }
    }
    // online softmax
#pragma unroll
    for (int r = 0; r < 4; r++) {
      float mx = fmaxf(fmaxf(s[0][r], s[1][r]), fmaxf(s[2][r], s[3][r]));
      mx = fmaxf(mx, __shfl_xor(mx, 1)); mx = fmaxf(mx, __shfl_xor(mx, 2));
      mx = fmaxf(mx, __shfl_xor(mx, 4)); mx = fmaxf(mx, __shfl_xor(mx, 8));
      float mnew = fmaxf(m_i[r], mx);
      float al = __expf(m_i[r] - mnew);
      float rs = 0.f;
#pragma unroll
      for (int tj = 0; tj < 4; tj++) {
        float p = __expf(s[tj][r] - mnew);
        s[tj][r] = p; rs += p;
      }
      rs += __shfl_xor(rs, 1); rs += __shfl_xor(rs, 2);
      rs += __shfl_xor(rs, 4); rs += __shfl_xor(rs, 8);
      l_i[r] = l_i[r] * al + rs;
      m_i[r] = mnew;
      o[0][r] *= al; o[1][r] *= al; o[2][r] *= al; o[3][r] *= al;
    }
    // P -> LDS (swizzled; same-wave write->read)
#pragma unroll
    for (int tj = 0; tj < 4; tj++) {
      int cch = tj * 2 + (lm >> 3);
      int cof = lm & 7;
#pragma unroll
      for (int r = 0; r < 4; r++) {
        int row = w * 16 + quad * 4 + r;
        int kp2 = (row & 7) ^ ((row >> 2) & 7);
        Ps[row * 64 + ((cch ^ kp2) << 3) + cof] = f2bf(s[tj][r]);
      }
    }
    // PV (globals chunk: only c<32 needed since ng<=8; P is 0 beyond ng)
    int kend = is_g ? 32 : 64;
#pragma unroll
    for (int k2 = 0; k2 < 64; k2 += 32) {
      if (k2 >= kend) break;
      int cb = (k2 >> 3) + quad;
      bf16x8 a = *(const bf16x8*)&Ps[arow * 64 + ((cb ^ kpr) << 3)];
#pragma unroll
      for (int tj = 0; tj < 4; tj++) {
        bf16x8 bfr = *(const bf16x8*)&Vs[buf][(tj * 16 + lm) * 64 + ((cb ^ sw) << 3)];
        o[tj] = __builtin_amdgcn_mfma_f32_16x16x32_bf16(a, bfr, o[tj], 0, 0, 0);
      }
    }
  }

  // coalesced epilogue: O -> Qs (dead, swizzled) -> 16B row stores
  __syncthreads();
#pragma unroll
  for (int r = 0; r < 4; r++) {
    float inv = 1.f / l_i[r];
    int row = w * 16 + quad * 4 + r;
    int kq2 = (row & 7) ^ ((row >> 2) & 7);
#pragma unroll
    for (int tj = 0; tj < 4; tj++) {
      int cch = tj * 2 + (lm >> 3);
      Qs[row * 64 + ((cch ^ kq2) << 3) + (lm & 7)] = f2bf(o[tj][r] * inv);
    }
  }
  __syncthreads();
#pragma unroll
  for (int it = 0; it < 2; it++) {
    int id = it * 256 + tid;
    int row = id >> 3, cch = id & 7;
    int kq2 = (row & 7) ^ ((row >> 2) & 7);
    uint4 vq = *(uint4*)&Qs[row * 64 + ((cch ^ kq2) << 3)];
    *(uint4*)&yb[((size_t)(i0 + row) * B_SZ + b) * E_DIM + h * HD + cch * 8] = vq;
  }
}

// ---------------------------------------------------------------------------
// residual add + LayerNorm; optional bf16 secondary output
// ---------------------------------------------------------------------------
__global__ __launch_bounds__(256) void add_ln_kernel(
    const float* __restrict__ a, const float* __restrict__ r,
    const float* __restrict__ g, const float* __restrict__ be,
    float* __restrict__ out, u16* __restrict__ outb) {
  int wave = threadIdx.x >> 6;
  int lane = threadIdx.x & 63;
  int row = blockIdx.x * 4 + wave;
  const float* ar = a + (size_t)row * E_DIM;
  const float* rr = r + (size_t)row * E_DIM;
  float vals[8];
  float s = 0.f;
#pragma unroll
  for (int t = 0; t < 8; t++) {
    vals[t] = ar[t * 64 + lane] + rr[t * 64 + lane];
    s += vals[t];
  }
#pragma unroll
  for (int o = 32; o >= 1; o >>= 1) s += __shfl_xor(s, o, 64);
  float mu = s * (1.f / E_DIM);
  float vs = 0.f;
#pragma unroll
  for (int t = 0; t < 8; t++) { float d = vals[t] - mu; vs += d * d; }
#pragma unroll
  for (int o = 32; o >= 1; o >>= 1) vs += __shfl_xor(vs, o, 64);
  float inv = rsqrtf(vs * (1.f / E_DIM) + 1e-5f);
  float* orow = out + (size_t)row * E_DIM;
  u16* obrow = outb ? outb + (size_t)row * E_DIM : nullptr;
#pragma unroll
  for (int t = 0; t < 8; t++) {
    int e = t * 64 + lane;
    float val = (vals[t] - mu) * inv * g[e] + be[e];
    orow[e] = val;
    if (obrow) obrow[e] = f2bf(val);
  }
}

// ---------------------------------------------------------------------------
// launch
// ---------------------------------------------------------------------------
extern "C" void kernel_launch(void* const* d_in, const int* in_sizes, int n_in,
                              void* d_out, int out_size, void* d_ws, size_t ws_size,
                              hipStream_t stream) {
  const float* x     = (const float*)d_in[0];
  const float* pos   = (const float*)d_in[1];
  const float* in_w  = (const float*)d_in[2];
  const float* in_b  = (const float*)d_in[3];
  const float* out_w = (const float*)d_in[4];
  const float* out_b = (const float*)d_in[5];
  const float* w1    = (const float*)d_in[6];
  const float* b1    = (const float*)d_in[7];
  const float* w2    = (const float*)d_in[8];
  const float* b2    = (const float*)d_in[9];
  const float* g1    = (const float*)d_in[10];
  const float* be1   = (const float*)d_in[11];
  const float* g2    = (const float*)d_in[12];
  const float* be2   = (const float*)d_in[13];
  float* out = (float*)d_out;

  // ws layout: xp 0..16M | xpb 16..24M (vtb reuses this window between QKV
  // and LN1) | qb 24..32M | kb 32..40M | vb 40..48M | ybf 48..56M |
  // aprj 56..72M | weights 72..80M
  char* base = (char*)d_ws;
  float* xp    = (float*)(base);
  u16*   xpb   = (u16*)(base + ((size_t)16 << 20));
  u16*   qb    = (u16*)(base + ((size_t)24 << 20));
  u16*   kb    = (u16*)(base + ((size_t)32 << 20));
  u16*   vb    = (u16*)(base + ((size_t)40 << 20));
  u16*   ybf   = (u16*)(base + ((size_t)48 << 20));
  float* aprj  = (float*)(base + ((size_t)56 << 20));
  u16*   inwb  = (u16*)(base + ((size_t)72 << 20));
  u16*   outwb = (u16*)(base + ((size_t)74 << 20));
  u16*   w1b   = (u16*)(base + ((size_t)76 << 20));
  u16*   w2b   = (u16*)(base + ((size_t)78 << 20));
  u16*   vtb   = xpb;     // dead window: QKV consumed xpb; LN1 rewrites later
  float* x1    = xp;
  u16*   x1b   = xpb;
  u16*   ff1b  = qb;      // 24M..56M
  float* ff2   = aprj;

  prep_kernel<<<7168, 256, 0, stream>>>(in_w, out_w, w1, w2, inwb, outwb, w1b, w2b,
                                        x, pos, xp, xpb);
  mfma_gemm<128, 12><<<dim3(64, 12), 256, 0, stream>>>(xpb, inwb, in_b, nullptr, nullptr,
                                                       NROWS, 1536, 512, 2, qb, kb, vb);
  vtrans_kernel<<<1024, 256, 0, stream>>>(vb, vtb);
  attn_mfma_kernel<<<dim3(32, 32), 256, 0, stream>>>(qb, kb, vtb, ybf);
  mfma_gemm<64, 8><<<dim3(64, 8), 256, 0, stream>>>(ybf, outwb, out_b, aprj, nullptr,
                                                    NROWS, 512, 512, 0, nullptr, nullptr, nullptr);
  add_ln_kernel<<<2048, 256, 0, stream>>>(xp, aprj, g1, be1, x1, x1b);
  mfma_gemm<128, 16><<<dim3(64, 16), 256, 0, stream>>>(x1b, w1b, b1, nullptr, ff1b,
                                                       NROWS, 2048, 512, 1, nullptr, nullptr, nullptr);
  mfma_gemm<64, 8><<<dim3(64, 8), 256, 0, stream>>>(ff1b, w2b, b2, ff2, nullptr,
                                                    NROWS, 512, 2048, 0, nullptr, nullptr, nullptr);
  add_ln_kernel<<<2048, 256, 0, stream>>>(x1, ff2, g2, be2, out, nullptr);
}